// Round 2
// 612.899 us; speedup vs baseline: 1.0185x; 1.0185x over previous
//
#include <hip/hip_runtime.h>

typedef __attribute__((ext_vector_type(8))) short short8;
typedef __attribute__((ext_vector_type(4))) float f32x4;

constexpr int Fdim = 128;
constexpr int Edim = 32;
constexpr int GB   = 16;     // b's per block (50000 = 16 * 3125 exactly)

// LDS arena (floats). Layout:
//   [0, 3072)    emb6: rows 0..5, [r][bl][e ^ ((bl>>2)<<3)]   (12,288 B)
//   [3072, 5120) kp:   float2 [side][bl][e ^ ((bl>>2)<<3)]    ( 8,192 B)
//   [5120, 5152) sbuf: [side][bl] = 1 + w0 + w1               (   128 B)
// W staging (4096 floats) overlaps [0,4096) before phase A; fenced by barriers.
constexpr int KP_BASE = 3072;
constexpr int SB_BASE = 5120;
constexpr int ARENA_F = 5152;   // 20,608 B -> up to 7 blocks/CU by LDS

static __device__ inline short f2bf(float x) {
    union { float f; unsigned u; } v; v.f = x;
    unsigned r = v.u + 0x7fffu + ((v.u >> 16) & 1u);   // RNE round to bf16
    return (short)(r >> 16);
}

// packed f32x2 -> bf16x2 (RNE), 1 VALU op for 2 elements
static __device__ __forceinline__ unsigned cvt2(float lo, float hi) {
    unsigned r;
    asm("v_cvt_pk_bf16_f32 %0, %1, %2" : "=v"(r) : "v"(lo), "v"(hi));
    return r;
}

static __device__ inline const float* row_ptr(int r, int b,
    const float* __restrict__ s1, const float* __restrict__ t1,
    const float* __restrict__ sh, const float* __restrict__ th,
    const float* __restrict__ sn, const float* __restrict__ tn)
{
    if (r == 0) return s1 + (size_t)b * Fdim;
    if (r == 1) return t1 + (size_t)b * Fdim;
    if (r < 6) {
        int i = r - 2;
        const float* base = (i < 2) ? sh : th;
        return base + (size_t)b * (2 * Fdim) + (size_t)(i & 1) * Fdim;
    }
    int i = r - 6;
    const float* base = (i < 10) ? sn : tn;
    if (i >= 10) i -= 10;
    return base + (size_t)b * (10 * Fdim) + (size_t)i * Fdim;
}

static __device__ __forceinline__ void load_row(f32x4 (&xa)[8], const float* rp, int kg) {
    #pragma unroll
    for (int kk = 0; kk < 4; kk++) {
        const float* p = rp + kk * 32 + kg * 8;
        xa[2 * kk]     = *(const f32x4*)p;
        xa[2 * kk + 1] = *(const f32x4*)(p + 4);
    }
}

static __device__ __forceinline__ void conv_row(short8 (&afk)[4], const f32x4 (&xa)[8]) {
    #pragma unroll
    for (int kk = 0; kk < 4; kk++) {
        union { unsigned u[4]; short8 s; } A;
        A.u[0] = cvt2(xa[2 * kk][0],     xa[2 * kk][1]);
        A.u[1] = cvt2(xa[2 * kk][2],     xa[2 * kk][3]);
        A.u[2] = cvt2(xa[2 * kk + 1][0], xa[2 * kk + 1][1]);
        A.u[3] = cvt2(xa[2 * kk + 1][2], xa[2 * kk + 1][3]);
        afk[kk] = A.s;
    }
}

__global__ __launch_bounds__(256, 4) void mmdne_kernel(
    const float* __restrict__ s_fts,
    const float* __restrict__ t_fts,
    const float* __restrict__ s_h_fts,
    const float* __restrict__ t_h_fts,
    const float* __restrict__ s_neg,
    const float* __restrict__ t_neg,
    const float* __restrict__ ev_t,
    const float* __restrict__ s_h_times,
    const float* __restrict__ t_h_times,
    const float* __restrict__ s_mask,
    const float* __restrict__ t_mask,
    const float* __restrict__ Wg,
    const float* __restrict__ bft,
    const float* __restrict__ av,
    const float* __restrict__ dels,
    const float* __restrict__ delt,
    float* __restrict__ out,
    int nB)
{
    __shared__ float arena[ARENA_F];

    const int tid  = threadIdx.x;
    const int lane = tid & 63;
    const int wid  = tid >> 6;
    const int b0   = blockIdx.x * GB;
    const int nlo  = lane & 15;   // MFMA: m (b_local) for A, n (e) for B, col for C
    const int kg   = lane >> 4;   // k-group 0..3

    // ---- Stage W (128x32 fp32, 16 KB) into LDS coalesced (overlaps emb6 region)
    {
        #pragma unroll
        for (int i = 0; i < 16; i++) arena[tid + 256 * i] = Wg[tid + 256 * i];
    }
    __syncthreads();

    // ---- Persistent bf16 B-fragments: bf[nt][kk], B[k][n], n=lane&15, k=kg*8+j
    short8 bf[2][4];
    #pragma unroll
    for (int nt = 0; nt < 2; nt++)
        #pragma unroll
        for (int kk = 0; kk < 4; kk++)
            #pragma unroll
            for (int j = 0; j < 8; j++)
                bf[nt][kk][j] = f2bf(arena[(kk * 32 + kg * 8 + j) * Edim + nt * 16 + nlo]);

    // scalar score-bias: sum_e b[e]*(a_cur[e] + a_his[e])   (wave-uniform)
    float bias_cb = 0.f;
    for (int j = 0; j < Edim; j++) bias_cb += bft[j] * (av[j] + av[Edim + j]);

    __syncthreads();   // done reading W from LDS

    // ---- Phase A: MFMA the 6 emb rows (s,t,s_h0,s_h1,t_h0,t_h1) into emb6
    for (int r = wid; r < 6; r += 4) {
        const float* rp = row_ptr(r, b0 + nlo, s_fts, t_fts, s_h_fts, t_h_fts, s_neg, t_neg);
        f32x4 xa[8]; load_row(xa, rp, kg);
        short8 afk[4]; conv_row(afk, xa);
        f32x4 a0 = {0.f,0.f,0.f,0.f}, a1 = {0.f,0.f,0.f,0.f};
        #pragma unroll
        for (int kk = 0; kk < 4; kk++) {
            a0 = __builtin_amdgcn_mfma_f32_16x16x32_bf16(afk[kk], bf[0][kk], a0, 0, 0, 0);
            a1 = __builtin_amdgcn_mfma_f32_16x16x32_bf16(afk[kk], bf[1][kk], a1, 0, 0, 0);
        }
        // C layout: col = nlo (e), row = kg*4 + reg (b_local); swizzle col by kg<<3
        #pragma unroll
        for (int reg = 0; reg < 4; reg++) {
            const int bl = kg * 4 + reg;
            arena[r * 512 + bl * 32 + (nlo ^ (kg << 3))]        = a0[reg];
            arena[r * 512 + bl * 32 + ((nlo + 16) ^ (kg << 3))] = a1[reg];
        }
    }
    __syncthreads();

    // ---- Phase B: scores/weights/p_lambda; write kp (k,p) + sbuf (S) for phase C
    {
        const int e    = lane & 31;
        const int half = lane >> 5;    // 0: s-side, 1: t-side
        const float a_cur = av[e];
        const float a_his = av[Edim + e];
        const float dl    = half ? delt[0] : dels[0];
        float2* kp = (float2*)(arena + KP_BASE);

        #pragma unroll
        for (int i = 0; i < 4; i++) {
            const int bl = wid * 4 + i;
            const int b  = b0 + bl;
            const int swz = (bl >> 2) << 3;   // = wid<<3

            float y[6];
            #pragma unroll
            for (int r = 0; r < 6; r++) y[r] = arena[r * 512 + bl * 32 + (e ^ swz)];

            float r0 = (half ? y[1] : y[0]) * a_cur;
            float r1 = (half ? y[4] : y[2]) * a_his;
            float r2 = (half ? y[5] : y[3]) * a_his;
            #pragma unroll
            for (int m = 1; m <= 16; m <<= 1) {
                r0 += __shfl_xor(r0, m);
                r1 += __shfl_xor(r1, m);
                r2 += __shfl_xor(r2, m);
            }

            const float et = ev_t[b];
            const float* htp = half ? t_h_times : s_h_times;
            const float* mkp = half ? t_mask : s_mask;
            const float h0t = htp[2 * b], h1t = htp[2 * b + 1];
            const float m0  = mkp[2 * b], m1  = mkp[2 * b + 1];
            const float d0 = fabsf(et - h0t), d1 = fabsf(et - h1t);
            const float sc0 = r0 + r1 + bias_cb, sc1 = r0 + r2 + bias_cb;
            float sim0 = expf(-dl * d0) * sc0; sim0 = sim0 >= 0.f ? sim0 : 0.2f * sim0;
            float sim1 = expf(-dl * d1) * sc1; sim1 = sim1 >= 0.f ? sim1 : 0.2f * sim1;
            const float mx = fmaxf(sim0, sim1);
            const float p0 = expf(sim0 - mx), p1 = expf(sim1 - mx);
            const float inv = 1.f / (p0 + p1);
            const float w0_ = p0 * inv * expf(dl * d0) * m0;
            const float w1_ = p1 * inv * expf(dl * d1) * m1;

            // p_lambda (uses s-side weights; lane 0 lives in half 0)
            {
                float q0 = y[0] - y[1]; q0 *= q0;
                float q1 = y[2] - y[1]; q1 *= q1;
                float q2 = y[3] - y[1]; q2 *= q2;
                float comb = q0 + w0_ * q1 + w1_ * q2;
                #pragma unroll
                for (int m = 1; m <= 16; m <<= 1) comb += __shfl_xor(comb, m);
                if (lane == 0) out[b] = -comb;
            }

            // expanded-distance precompute for the neg epilogue:
            //   k = A^2 + w0*H0^2 + w1*H1^2 ; p = A + w0*H0 + w1*H1 ; S = 1 + w0 + w1
            const float A_  = half ? y[1] : y[0];
            const float H0_ = half ? y[4] : y[2];
            const float H1_ = half ? y[5] : y[3];
            const float k_  = A_ * A_ + w0_ * H0_ * H0_ + w1_ * H1_ * H1_;
            const float p_  = A_ + w0_ * H0_ + w1_ * H1_;
            kp[half * 512 + bl * 32 + (e ^ swz)] = make_float2(k_, p_);
            if (e == 0) arena[SB_BASE + half * 16 + bl] = 1.f + w0_ + w1_;
        }
    }
    __syncthreads();

    // ---- Phase C: stream the 20 neg rows; consume MFMA output in-register.
    // n_lambda[b][n] = -( (k0+k1) - 2*(a0*p0 + a1*p1) + S*(a0^2 + a1^2) ) summed over e
    {
        const float2* kp = (const float2*)(arena + KP_BASE);
        f32x4 xa[8];
        int r = 6 + wid;
        load_row(xa, row_ptr(r, b0 + nlo, s_fts, t_fts, s_h_fts, t_h_fts, s_neg, t_neg), kg);
        for (; r < 26; r += 4) {
            short8 afk[4];
            conv_row(afk, xa);                      // xa dead after this
            if (r + 4 < 26)                          // issue next row's loads early
                load_row(xa, row_ptr(r + 4, b0 + nlo, s_fts, t_fts, s_h_fts, t_h_fts, s_neg, t_neg), kg);

            f32x4 a0 = {0.f,0.f,0.f,0.f}, a1 = {0.f,0.f,0.f,0.f};
            #pragma unroll
            for (int kk = 0; kk < 4; kk++) {
                a0 = __builtin_amdgcn_mfma_f32_16x16x32_bf16(afk[kk], bf[0][kk], a0, 0, 0, 0);
                a1 = __builtin_amdgcn_mfma_f32_16x16x32_bf16(afk[kk], bf[1][kk], a1, 0, 0, 0);
            }

            const int sideH = (r < 16) ? 1 : 0;      // s_neg pairs with t-side, t_neg with s-side
            const int n     = (r < 16) ? (r - 6) : (r - 16);
            float* on = out + nB + (r < 16 ? (size_t)nB * 10 : (size_t)0);

            #pragma unroll
            for (int reg = 0; reg < 4; reg++) {
                const int bl = kg * 4 + reg;
                const float2 kp0 = kp[sideH * 512 + bl * 32 + (nlo ^ (kg << 3))];
                const float2 kp1 = kp[sideH * 512 + bl * 32 + ((nlo + 16) ^ (kg << 3))];
                const float S    = arena[SB_BASE + sideH * 16 + bl];
                const float q0 = a0[reg], q1 = a1[reg];
                float part = (kp0.x + kp1.x)
                           - 2.f * (q0 * kp0.y + q1 * kp1.y)
                           + S * (q0 * q0 + q1 * q1);
                #pragma unroll
                for (int m = 1; m <= 8; m <<= 1) part += __shfl_xor(part, m);
                if (nlo == reg) on[(size_t)(b0 + bl) * 10 + n] = -part;
            }
        }
    }
}

extern "C" void kernel_launch(void* const* d_in, const int* in_sizes, int n_in,
                              void* d_out, int out_size, void* d_ws, size_t ws_size,
                              hipStream_t stream) {
    const float* s_fts     = (const float*)d_in[0];
    const float* t_fts     = (const float*)d_in[1];
    const float* s_h_fts   = (const float*)d_in[2];
    const float* t_h_fts   = (const float*)d_in[3];
    const float* s_neg     = (const float*)d_in[4];
    const float* t_neg     = (const float*)d_in[5];
    const float* ev_t      = (const float*)d_in[6];
    const float* s_h_times = (const float*)d_in[7];
    const float* t_h_times = (const float*)d_in[8];
    const float* s_mask    = (const float*)d_in[9];
    const float* t_mask    = (const float*)d_in[10];
    const float* Wg        = (const float*)d_in[11];
    const float* bft       = (const float*)d_in[12];
    const float* av        = (const float*)d_in[13];
    const float* dels      = (const float*)d_in[14];
    const float* delt      = (const float*)d_in[15];

    const int nB = in_sizes[6];             // B = 50000
    const int blocks = (nB + GB - 1) / GB;  // 3125, exact

    mmdne_kernel<<<blocks, 256, 0, stream>>>(
        s_fts, t_fts, s_h_fts, t_h_fts, s_neg, t_neg, ev_t,
        s_h_times, t_h_times, s_mask, t_mask, Wg, bft, av, dels, delt,
        (float*)d_out, nB);
}